// Round 7
// baseline (546.649 us; speedup 1.0000x reference)
//
#include <hip/hip_runtime.h>
#include <hip/hip_bf16.h>

// ---------------- problem constants ----------------
#define B_   4
#define T_   2048
#define C_   1024
#define NH_  16
#define HS_  64
#define M_   8192      // B*T
#define N1_  3072      // 3*C
#define BH_  64        // B*NH

typedef __attribute__((ext_vector_type(8))) short short8;   // 8 bf16
typedef __attribute__((ext_vector_type(4))) short short4v;  // 4 bf16
typedef __attribute__((ext_vector_type(4))) float f32x4;

__device__ __forceinline__ short f2bf(float f) {   // RNE
  unsigned u = __float_as_uint(f);
  unsigned r = (u + 0x7fffu + ((u >> 16) & 1u)) >> 16;
  return (short)r;
}
// packed f32x2 -> bf16x2 (v_cvt_pk_bf16_f32), low word = a
__device__ __forceinline__ unsigned pk_bf16(float a, float b) {
  __hip_bfloat162 h = __float22bfloat162_rn(make_float2(a, b));
  union { __hip_bfloat162 h2; unsigned u; } cv; cv.h2 = h; return cv.u;
}

// async global->LDS, 16B per lane (dest = wave-uniform base + lane*16)
typedef __attribute__((address_space(1))) unsigned int as1_uint;
typedef __attribute__((address_space(3))) unsigned int as3_uint;
__device__ __forceinline__ void g2l16(const void* g, void* l) {
  __builtin_amdgcn_global_load_lds((as1_uint*)g, (as3_uint*)l, 16, 0, 0);
}

// ============================================================
// f32 -> bf16, 8 elements/thread, n % 2048 == 0
// ============================================================
__global__ __launch_bounds__(256) void conv_bf16(
    const float* __restrict__ src, short* __restrict__ dst)
{
  const size_t i = ((size_t)blockIdx.x * 256 + threadIdx.x) * 8;
  const f32x4 a = *(const f32x4*)&src[i];
  const f32x4 b = *(const f32x4*)&src[i + 4];
  short8 o;
  o[0] = f2bf(a[0]); o[1] = f2bf(a[1]); o[2] = f2bf(a[2]); o[3] = f2bf(a[3]);
  o[4] = f2bf(b[0]); o[5] = f2bf(b[1]); o[6] = f2bf(b[2]); o[7] = f2bf(b[3]);
  *(short8*)&dst[i] = o;
}

// ============================================================
// QKV GEMM (grid = (M/128, 24)): qkv = X @ Wqkv^T + bqkv
// X [M,C] bf16. Q,K -> [BH][T][HS]; V -> TRANSPOSED [BH][HS][T].
// ============================================================
__global__ __launch_bounds__(256) void qkv_gemm(
    const short* __restrict__ X,    // [M, C] bf16
    const short* __restrict__ W,    // [N1, C] bf16
    const float* __restrict__ bias, // [N1] f32
    short* __restrict__ Qo, short* __restrict__ Ko, short* __restrict__ Vt)
{
  __shared__ short As[128 * 32];
  __shared__ short Bs[128 * 32];
  const int tid = threadIdx.x;
  const int lane = tid & 63;
  const int wid = tid >> 6;
  const int wy = wid >> 1, wx = wid & 1;
  const int lq = lane >> 4, lm = lane & 15;
  const int row0 = blockIdx.x * 128;
  const int col0 = blockIdx.y * 128;

  f32x4 acc[4][4] = {};

  const int c0 = tid, c1 = tid + 256;
  const int ar0 = c0 >> 2, ak0 = (c0 & 3) << 3;
  const int ar1 = c1 >> 2, ak1 = (c1 & 3) << 3;

  for (int k0 = 0; k0 < C_; k0 += 32) {
    __syncthreads();
    g2l16(&X[(size_t)(row0 + ar0) * C_ + k0 + ak0], &As[c0 * 8]);
    g2l16(&X[(size_t)(row0 + ar1) * C_ + k0 + ak1], &As[c1 * 8]);
    g2l16(&W[(size_t)(col0 + ar0) * C_ + k0 + ak0], &Bs[c0 * 8]);
    g2l16(&W[(size_t)(col0 + ar1) * C_ + k0 + ak1], &Bs[c1 * 8]);
    __syncthreads();

    short8 af[4], bfr[4];
#pragma unroll
    for (int mi = 0; mi < 4; ++mi)
      af[mi] = *(const short8*)&As[(wy * 64 + mi * 16 + lm) * 32 + lq * 8];
#pragma unroll
    for (int ni = 0; ni < 4; ++ni)
      bfr[ni] = *(const short8*)&Bs[(wx * 64 + ni * 16 + lm) * 32 + lq * 8];
#pragma unroll
    for (int mi = 0; mi < 4; ++mi)
#pragma unroll
      for (int ni = 0; ni < 4; ++ni)
        acc[mi][ni] = __builtin_amdgcn_mfma_f32_16x16x32_bf16(af[mi], bfr[ni], acc[mi][ni], 0, 0, 0);
  }

#pragma unroll
  for (int ni = 0; ni < 4; ++ni) {
    const int n = col0 + wx * 64 + ni * 16 + lm;
    const float bv = bias[n];
    const int sel = n >> 10;              // 0=Q, 1=K, 2=V (uniform per tile)
    const int cc = n & (C_ - 1);
    const int h = cc >> 6, d = cc & 63;
    if (sel == 2) {
      // V transposed: Vt[(bh*64 + d)*T + t], 4 consecutive t per lane
#pragma unroll
      for (int mi = 0; mi < 4; ++mi) {
        const int m0 = row0 + wy * 64 + mi * 16 + lq * 4;
        const int b = m0 >> 11, t0 = m0 & (T_ - 1);
        const int bh = b * NH_ + h;
        short4v o;
#pragma unroll
        for (int i = 0; i < 4; ++i) o[i] = f2bf(acc[mi][ni][i] + bv);
        *(short4v*)&Vt[((size_t)bh * HS_ + d) * T_ + t0] = o;
      }
    } else {
      short* dst = (sel == 0) ? Qo : Ko;
#pragma unroll
      for (int mi = 0; mi < 4; ++mi) {
#pragma unroll
        for (int i = 0; i < 4; ++i) {
          const int m = row0 + wy * 64 + mi * 16 + lq * 4 + i;
          const int b = m >> 11, t = m & (T_ - 1);
          const int bh = b * NH_ + h;
          dst[((size_t)bh * T_ + t) * HS_ + d] = f2bf(acc[mi][ni][i] + bv);
        }
      }
    }
  }
}

// ============================================================
// Proj GEMM (grid = (M/128, 8)): out = Y @ Wproj^T + bproj -> f32
// ============================================================
__global__ __launch_bounds__(256) void proj_gemm(
    const short* __restrict__ Y,    // [M, C] bf16
    const short* __restrict__ W,    // [C, C] bf16
    const float* __restrict__ bias, // [C] f32
    float* __restrict__ Out)        // [M, C] f32
{
  __shared__ short As[128 * 32];
  __shared__ short Bs[128 * 32];
  const int tid = threadIdx.x;
  const int lane = tid & 63;
  const int wid = tid >> 6;
  const int wy = wid >> 1, wx = wid & 1;
  const int lq = lane >> 4, lm = lane & 15;
  const int row0 = blockIdx.x * 128;
  const int col0 = blockIdx.y * 128;

  f32x4 acc[4][4] = {};

  const int c0 = tid, c1 = tid + 256;
  const int ar0 = c0 >> 2, ak0 = (c0 & 3) << 3;
  const int ar1 = c1 >> 2, ak1 = (c1 & 3) << 3;

  for (int k0 = 0; k0 < C_; k0 += 32) {
    __syncthreads();
    g2l16(&Y[(size_t)(row0 + ar0) * C_ + k0 + ak0], &As[c0 * 8]);
    g2l16(&Y[(size_t)(row0 + ar1) * C_ + k0 + ak1], &As[c1 * 8]);
    g2l16(&W[(size_t)(col0 + ar0) * C_ + k0 + ak0], &Bs[c0 * 8]);
    g2l16(&W[(size_t)(col0 + ar1) * C_ + k0 + ak1], &Bs[c1 * 8]);
    __syncthreads();

    short8 af[4], bfr[4];
#pragma unroll
    for (int mi = 0; mi < 4; ++mi)
      af[mi] = *(const short8*)&As[(wy * 64 + mi * 16 + lm) * 32 + lq * 8];
#pragma unroll
    for (int ni = 0; ni < 4; ++ni)
      bfr[ni] = *(const short8*)&Bs[(wx * 64 + ni * 16 + lm) * 32 + lq * 8];
#pragma unroll
    for (int mi = 0; mi < 4; ++mi)
#pragma unroll
      for (int ni = 0; ni < 4; ++ni)
        acc[mi][ni] = __builtin_amdgcn_mfma_f32_16x16x32_bf16(af[mi], bfr[ni], acc[mi][ni], 0, 0, 0);
  }

#pragma unroll
  for (int ni = 0; ni < 4; ++ni) {
    const int n = col0 + wx * 64 + ni * 16 + lm;
    const float bv = bias[n];
#pragma unroll
    for (int mi = 0; mi < 4; ++mi) {
#pragma unroll
      for (int i = 0; i < 4; ++i) {
        const int m = row0 + wy * 64 + mi * 16 + lq * 4 + i;
        Out[(size_t)m * C_ + n] = acc[mi][ni][i] + bv;
      }
    }
  }
}

// ============================================================
// Flash attention, S-TRANSPOSED formulation. grid = (16, BH), no LDS.
// Block = two q-tiles (qt = 31-x then x => 33 kv-iters, balanced).
// 4 waves x 16 q-rows. S^T = mfma(K_frag, Q_frag): q = lane&15,
// kv = quad*4+i+16*ni  -> softmax reduction is IN-REGISTER + 2 shfl_xor.
// P is natively in B-layout of mfma_16x16x16bf16_1k (k=quad*4+j):
// PV = mfma(V^T_frag, P_frag) -> O^T, no LDS transpose at all.
// Q,K: [BH][T][HS]; Vt: [BH][HS][T]. Y out: bf16 [B][T][C] at col h*64+d.
// ============================================================
__global__ __launch_bounds__(256) void attn(
    const short* __restrict__ Qg, const short* __restrict__ Kg,
    const short* __restrict__ Vg, short* __restrict__ Yo)
{
  const int tid = threadIdx.x;
  const int lane = tid & 63;
  const int w = tid >> 6;
  const int lq = lane >> 4, lm = lane & 15;
  const int bh = blockIdx.y;
  const int b = bh >> 4, h = bh & 15;
  const size_t base = (size_t)bh * T_ * HS_;
  const short* __restrict__ Kb = Kg + base;
  const short* __restrict__ Vb = Vg + base;
  const float sf = 0.125f * 1.44269504089f;  // 1/sqrt(HS) * log2(e)

#pragma unroll 1
  for (int half = 0; half < 2; ++half) {
    const int qt = half ? (int)blockIdx.x : 31 - (int)blockIdx.x;
    const int q0 = qt * 64;
    const int q = q0 + w * 16 + lm;          // this lane's q-row

    // Q fragment (B-layout): lane holds Q[q][lq*8+j (+32)]
    const short8 qf0 = *(const short8*)&Qg[base + (size_t)q * HS_ + lq * 8];
    const short8 qf1 = *(const short8*)&Qg[base + (size_t)q * HS_ + 32 + lq * 8];

    float m_run = -3.0e38f, l_run = 0.0f;    // per-lane (per q-row) state
    f32x4 o_acc[4] = {};                     // O^T: d = di*16 + lq*4 + i, col q

#pragma unroll 1
    for (int kt = 0; kt <= qt; ++kt) {
      const int kv0 = kt * 64;

      // ---- V^T fragments for PV (A-layout of 16x16x16): issue early ----
      // vfr[di][ni] = V^T[di*16+lm][kv0 + ni*16 + lq*4 .. +3]
      short4v vfr[4][4];
#pragma unroll
      for (int di = 0; di < 4; ++di)
#pragma unroll
        for (int ni = 0; ni < 4; ++ni)
          vfr[di][ni] = *(const short4v*)&Vb[(size_t)(di * 16 + lm) * T_ + kv0 + ni * 16 + lq * 4];

      // ---- S^T = K Q^T: sv[ni][i] = S[q][kv0 + ni*16 + lq*4 + i] ----
      f32x4 sv[4];
#pragma unroll
      for (int ni = 0; ni < 4; ++ni) {
        const size_t kr = (size_t)(kv0 + ni * 16 + lm) * HS_;
        const short8 kf0 = *(const short8*)&Kb[kr + lq * 8];
        const short8 kf1 = *(const short8*)&Kb[kr + 32 + lq * 8];
        f32x4 s = {};
        s = __builtin_amdgcn_mfma_f32_16x16x32_bf16(kf0, qf0, s, 0, 0, 0);
        sv[ni] = __builtin_amdgcn_mfma_f32_16x16x32_bf16(kf1, qf1, s, 0, 0, 0);
      }

      if (kt == qt) {   // causal mask on diagonal tile (raw scores)
#pragma unroll
        for (int ni = 0; ni < 4; ++ni) {
          const int kvb = kv0 + ni * 16 + lq * 4;
#pragma unroll
          for (int i = 0; i < 4; ++i)
            if (kvb + i > q) sv[ni][i] = -3.0e38f;
        }
      }

      // ---- online softmax: in-register reduce + 2 cross-quad shuffles ----
      float v = fmaxf(fmaxf(fmaxf(sv[0][0], sv[0][1]), fmaxf(sv[0][2], sv[0][3])),
                      fmaxf(fmaxf(sv[1][0], sv[1][1]), fmaxf(sv[1][2], sv[1][3])));
      v = fmaxf(v, fmaxf(fmaxf(fmaxf(sv[2][0], sv[2][1]), fmaxf(sv[2][2], sv[2][3])),
                         fmaxf(fmaxf(sv[3][0], sv[3][1]), fmaxf(sv[3][2], sv[3][3]))));
      v = fmaxf(v, __shfl_xor(v, 16));
      v = fmaxf(v, __shfl_xor(v, 32));
      const float mnew = fmaxf(m_run, v);
      const float alpha = __builtin_amdgcn_exp2f((m_run - mnew) * sf);
      const float nb = -mnew * sf;
      m_run = mnew;

      // P = exp2(sf*s - sf*mnew)  (scale folded into exp2 arg)
#pragma unroll
      for (int ni = 0; ni < 4; ++ni)
#pragma unroll
        for (int i = 0; i < 4; ++i)
          sv[ni][i] = __builtin_amdgcn_exp2f(__builtin_fmaf(sv[ni][i], sf, nb));

      float s = ((sv[0][0] + sv[0][1]) + (sv[0][2] + sv[0][3]))
              + ((sv[1][0] + sv[1][1]) + (sv[1][2] + sv[1][3]))
              + ((sv[2][0] + sv[2][1]) + (sv[2][2] + sv[2][3]))
              + ((sv[3][0] + sv[3][1]) + (sv[3][2] + sv[3][3]));
      s += __shfl_xor(s, 16);
      s += __shfl_xor(s, 32);
      l_run = l_run * alpha + s;

#pragma unroll
      for (int di = 0; di < 4; ++di)
#pragma unroll
        for (int i = 0; i < 4; ++i)
          o_acc[di][i] *= alpha;

      // ---- pack P to bf16 (packed cvt), already in B-layout ----
      short4v p4[4];
#pragma unroll
      for (int ni = 0; ni < 4; ++ni) {
        union { short4v s4; unsigned u[2]; } pk;
        pk.u[0] = pk_bf16(sv[ni][0], sv[ni][1]);
        pk.u[1] = pk_bf16(sv[ni][2], sv[ni][3]);
        p4[ni] = pk.s4;
      }

      // ---- O^T += V^T P^T  (16x16x16 bf16 MFMA) ----
#pragma unroll
      for (int di = 0; di < 4; ++di)
#pragma unroll
        for (int ni = 0; ni < 4; ++ni)
          o_acc[di] = __builtin_amdgcn_mfma_f32_16x16x16bf16_1k(vfr[di][ni], p4[ni], o_acc[di], 0, 0, 0);
    }

    // ---- epilogue: normalize, store Y bf16 [B,T,C], 4x b64 per lane ----
    const float rl = 1.0f / l_run;
    const size_t rowo = ((size_t)(b * T_ + q)) * C_ + h * HS_;
#pragma unroll
    for (int di = 0; di < 4; ++di) {
      union { short4v s4; unsigned u[2]; } pk;
      pk.u[0] = pk_bf16(o_acc[di][0] * rl, o_acc[di][1] * rl);
      pk.u[1] = pk_bf16(o_acc[di][2] * rl, o_acc[di][3] * rl);
      *(short4v*)&Yo[rowo + di * 16 + lq * 4] = pk.s4;
    }
  }
}

// ============================================================
extern "C" void kernel_launch(void* const* d_in, const int* in_sizes, int n_in,
                              void* d_out, int out_size, void* d_ws, size_t ws_size,
                              hipStream_t stream) {
  (void)in_sizes; (void)n_in; (void)out_size;
  const float* x     = (const float*)d_in[0];
  const float* Wqkv  = (const float*)d_in[1];
  const float* bqkv  = (const float*)d_in[2];
  const float* Wproj = (const float*)d_in[3];
  const float* bproj = (const float*)d_in[4];
  float* out = (float*)d_out;

  const size_t nWq = (size_t)N1_ * C_;        // 3,145,728
  const size_t nWp = (size_t)C_ * C_;         // 1,048,576
  const size_t nFull = (size_t)M_ * C_;       // 8,388,608
  const size_t nB = (size_t)T_ * C_;          // 2,097,152 per batch

  dim3 blk(256);
  const size_t need_batched = (nWq + nWp + 4 * nFull) * sizeof(short); // 75.6 MB

  if (ws_size >= need_batched) {
    // -------- fully batched pipeline --------
    short* Wq_bf = (short*)d_ws;
    short* Wp_bf = Wq_bf + nWq;
    short* S0    = Wp_bf + nWp;      // x_bf, later Y
    short* Qw    = S0 + nFull;
    short* Kw    = Qw + nFull;
    short* Vw    = Kw + nFull;       // transposed [BH][HS][T]

    conv_bf16<<<dim3((int)(nWq / 2048)), blk, 0, stream>>>(Wqkv, Wq_bf);
    conv_bf16<<<dim3((int)(nWp / 2048)), blk, 0, stream>>>(Wproj, Wp_bf);
    conv_bf16<<<dim3((int)(nFull / 2048)), blk, 0, stream>>>(x, S0);
    qkv_gemm<<<dim3(M_ / 128, N1_ / 128), blk, 0, stream>>>(S0, Wq_bf, bqkv, Qw, Kw, Vw);
    attn<<<dim3(16, BH_), blk, 0, stream>>>(Qw, Kw, Vw, S0);
    proj_gemm<<<dim3(M_ / 128, C_ / 128), blk, 0, stream>>>(S0, Wp_bf, bproj, out);
  } else {
    // -------- per-batch fallback (25.2 MB ws) --------
    short* Wq_bf = (short*)d_ws;
    short* Wp_bf = Wq_bf + nWq;
    short* S0    = Wp_bf + nWp;      // x_bf, later Y (per batch)
    short* Qw    = S0 + nB;
    short* Kw    = Qw + nB;
    short* Vw    = Kw + nB;

    conv_bf16<<<dim3((int)(nWq / 2048)), blk, 0, stream>>>(Wqkv, Wq_bf);
    conv_bf16<<<dim3((int)(nWp / 2048)), blk, 0, stream>>>(Wproj, Wp_bf);
    for (int b = 0; b < B_; ++b) {
      const float* xb = x   + (size_t)b * nB;
      float*       ob = out + (size_t)b * nB;
      conv_bf16<<<dim3((int)(nB / 2048)), blk, 0, stream>>>(xb, S0);
      qkv_gemm<<<dim3(T_ / 128, N1_ / 128), blk, 0, stream>>>(S0, Wq_bf, bqkv, Qw, Kw, Vw);
      attn<<<dim3(16, NH_), blk, 0, stream>>>(Qw, Kw, Vw, S0);
      proj_gemm<<<dim3(T_ / 128, C_ / 128), blk, 0, stream>>>(S0, Wp_bf, bproj, ob);
    }
  }
}

// Round 8
// 276.552 us; speedup vs baseline: 1.9767x; 1.9767x over previous
//
#include <hip/hip_runtime.h>
#include <hip/hip_bf16.h>

// ---------------- problem constants ----------------
#define B_   4
#define T_   2048
#define C_   1024
#define NH_  16
#define HS_  64
#define M_   8192      // B*T
#define N1_  3072      // 3*C
#define BH_  64        // B*NH

typedef __attribute__((ext_vector_type(8))) short short8;   // 8 bf16
typedef __attribute__((ext_vector_type(4))) short short4v;  // 4 bf16
typedef __attribute__((ext_vector_type(4))) float f32x4;

__device__ __forceinline__ short f2bf(float f) {   // RNE
  unsigned u = __float_as_uint(f);
  unsigned r = (u + 0x7fffu + ((u >> 16) & 1u)) >> 16;
  return (short)r;
}
// packed f32x2 -> bf16x2 (v_cvt_pk_bf16_f32), low word = a
__device__ __forceinline__ unsigned pk_bf16(float a, float b) {
  __hip_bfloat162 h = __float22bfloat162_rn(make_float2(a, b));
  union { __hip_bfloat162 h2; unsigned u; } cv; cv.h2 = h; return cv.u;
}

// async global->LDS, 16B per lane (dest = wave-uniform base + lane*16)
typedef __attribute__((address_space(1))) unsigned int as1_uint;
typedef __attribute__((address_space(3))) unsigned int as3_uint;
__device__ __forceinline__ void g2l16(const void* g, void* l) {
  __builtin_amdgcn_global_load_lds((as1_uint*)g, (as3_uint*)l, 16, 0, 0);
}

// ============================================================
// f32 -> bf16, 8 elements/thread, n % 2048 == 0
// ============================================================
__global__ __launch_bounds__(256) void conv_bf16(
    const float* __restrict__ src, short* __restrict__ dst)
{
  const size_t i = ((size_t)blockIdx.x * 256 + threadIdx.x) * 8;
  const f32x4 a = *(const f32x4*)&src[i];
  const f32x4 b = *(const f32x4*)&src[i + 4];
  short8 o;
  o[0] = f2bf(a[0]); o[1] = f2bf(a[1]); o[2] = f2bf(a[2]); o[3] = f2bf(a[3]);
  o[4] = f2bf(b[0]); o[5] = f2bf(b[1]); o[6] = f2bf(b[2]); o[7] = f2bf(b[3]);
  *(short8*)&dst[i] = o;
}

// ============================================================
// QKV GEMM (grid = (M/128, 24)): qkv = X @ Wqkv^T + bqkv
// X [M,C] bf16. Q,K -> [BH][T][HS]; V -> TRANSPOSED [BH][HS][T].
// ============================================================
__global__ __launch_bounds__(256) void qkv_gemm(
    const short* __restrict__ X,    // [M, C] bf16
    const short* __restrict__ W,    // [N1, C] bf16
    const float* __restrict__ bias, // [N1] f32
    short* __restrict__ Qo, short* __restrict__ Ko, short* __restrict__ Vt)
{
  __shared__ short As[128 * 32];
  __shared__ short Bs[128 * 32];
  const int tid = threadIdx.x;
  const int lane = tid & 63;
  const int wid = tid >> 6;
  const int wy = wid >> 1, wx = wid & 1;
  const int lq = lane >> 4, lm = lane & 15;
  const int row0 = blockIdx.x * 128;
  const int col0 = blockIdx.y * 128;

  f32x4 acc[4][4] = {};

  const int c0 = tid, c1 = tid + 256;
  const int ar0 = c0 >> 2, ak0 = (c0 & 3) << 3;
  const int ar1 = c1 >> 2, ak1 = (c1 & 3) << 3;

  for (int k0 = 0; k0 < C_; k0 += 32) {
    __syncthreads();
    g2l16(&X[(size_t)(row0 + ar0) * C_ + k0 + ak0], &As[c0 * 8]);
    g2l16(&X[(size_t)(row0 + ar1) * C_ + k0 + ak1], &As[c1 * 8]);
    g2l16(&W[(size_t)(col0 + ar0) * C_ + k0 + ak0], &Bs[c0 * 8]);
    g2l16(&W[(size_t)(col0 + ar1) * C_ + k0 + ak1], &Bs[c1 * 8]);
    __syncthreads();

    short8 af[4], bfr[4];
#pragma unroll
    for (int mi = 0; mi < 4; ++mi)
      af[mi] = *(const short8*)&As[(wy * 64 + mi * 16 + lm) * 32 + lq * 8];
#pragma unroll
    for (int ni = 0; ni < 4; ++ni)
      bfr[ni] = *(const short8*)&Bs[(wx * 64 + ni * 16 + lm) * 32 + lq * 8];
#pragma unroll
    for (int mi = 0; mi < 4; ++mi)
#pragma unroll
      for (int ni = 0; ni < 4; ++ni)
        acc[mi][ni] = __builtin_amdgcn_mfma_f32_16x16x32_bf16(af[mi], bfr[ni], acc[mi][ni], 0, 0, 0);
  }

#pragma unroll
  for (int ni = 0; ni < 4; ++ni) {
    const int n = col0 + wx * 64 + ni * 16 + lm;
    const float bv = bias[n];
    const int sel = n >> 10;              // 0=Q, 1=K, 2=V (uniform per tile)
    const int cc = n & (C_ - 1);
    const int h = cc >> 6, d = cc & 63;
    if (sel == 2) {
      // V transposed: Vt[(bh*64 + d)*T + t], 4 consecutive t per lane
#pragma unroll
      for (int mi = 0; mi < 4; ++mi) {
        const int m0 = row0 + wy * 64 + mi * 16 + lq * 4;
        const int b = m0 >> 11, t0 = m0 & (T_ - 1);
        const int bh = b * NH_ + h;
        short4v o;
#pragma unroll
        for (int i = 0; i < 4; ++i) o[i] = f2bf(acc[mi][ni][i] + bv);
        *(short4v*)&Vt[((size_t)bh * HS_ + d) * T_ + t0] = o;
      }
    } else {
      short* dst = (sel == 0) ? Qo : Ko;
#pragma unroll
      for (int mi = 0; mi < 4; ++mi) {
#pragma unroll
        for (int i = 0; i < 4; ++i) {
          const int m = row0 + wy * 64 + mi * 16 + lq * 4 + i;
          const int b = m >> 11, t = m & (T_ - 1);
          const int bh = b * NH_ + h;
          dst[((size_t)bh * T_ + t) * HS_ + d] = f2bf(acc[mi][ni][i] + bv);
        }
      }
    }
  }
}

// ============================================================
// Proj GEMM (grid = (M/128, 8)): out = Y @ Wproj^T + bproj -> f32
// ============================================================
__global__ __launch_bounds__(256) void proj_gemm(
    const short* __restrict__ Y,    // [M, C] bf16
    const short* __restrict__ W,    // [C, C] bf16
    const float* __restrict__ bias, // [C] f32
    float* __restrict__ Out)        // [M, C] f32
{
  __shared__ short As[128 * 32];
  __shared__ short Bs[128 * 32];
  const int tid = threadIdx.x;
  const int lane = tid & 63;
  const int wid = tid >> 6;
  const int wy = wid >> 1, wx = wid & 1;
  const int lq = lane >> 4, lm = lane & 15;
  const int row0 = blockIdx.x * 128;
  const int col0 = blockIdx.y * 128;

  f32x4 acc[4][4] = {};

  const int c0 = tid, c1 = tid + 256;
  const int ar0 = c0 >> 2, ak0 = (c0 & 3) << 3;
  const int ar1 = c1 >> 2, ak1 = (c1 & 3) << 3;

  for (int k0 = 0; k0 < C_; k0 += 32) {
    __syncthreads();
    g2l16(&Y[(size_t)(row0 + ar0) * C_ + k0 + ak0], &As[c0 * 8]);
    g2l16(&Y[(size_t)(row0 + ar1) * C_ + k0 + ak1], &As[c1 * 8]);
    g2l16(&W[(size_t)(col0 + ar0) * C_ + k0 + ak0], &Bs[c0 * 8]);
    g2l16(&W[(size_t)(col0 + ar1) * C_ + k0 + ak1], &Bs[c1 * 8]);
    __syncthreads();

    short8 af[4], bfr[4];
#pragma unroll
    for (int mi = 0; mi < 4; ++mi)
      af[mi] = *(const short8*)&As[(wy * 64 + mi * 16 + lm) * 32 + lq * 8];
#pragma unroll
    for (int ni = 0; ni < 4; ++ni)
      bfr[ni] = *(const short8*)&Bs[(wx * 64 + ni * 16 + lm) * 32 + lq * 8];
#pragma unroll
    for (int mi = 0; mi < 4; ++mi)
#pragma unroll
      for (int ni = 0; ni < 4; ++ni)
        acc[mi][ni] = __builtin_amdgcn_mfma_f32_16x16x32_bf16(af[mi], bfr[ni], acc[mi][ni], 0, 0, 0);
  }

#pragma unroll
  for (int ni = 0; ni < 4; ++ni) {
    const int n = col0 + wx * 64 + ni * 16 + lm;
    const float bv = bias[n];
#pragma unroll
    for (int mi = 0; mi < 4; ++mi) {
#pragma unroll
      for (int i = 0; i < 4; ++i) {
        const int m = row0 + wy * 64 + mi * 16 + lq * 4 + i;
        Out[(size_t)m * C_ + n] = acc[mi][ni][i] + bv;
      }
    }
  }
}

// ============================================================
// Flash attention, S^T form + LDS-staged K/V + 1-tile prefetch.
// grid = (16, BH); block = two q-tiles (31-x, then x) => 33 kv-iters.
// S^T = mfma(K,Q): q=lane&15, kv=quad*4+i+16ni -> register softmax.
// P natively B-layout of 16x16x16bf16_1k; PV = mfma(V^T, P) -> O^T.
// K/V staged: coalesced short8 global loads -> padded LDS rows (72
// shorts) -> bank-even b128/b64 fragment reads shared by 4 waves.
// Q,K: [BH][T][HS]; Vt: [BH][HS][T]. Y out bf16 [B][T][C] col h*64+d.
// ============================================================
#define LDK 72   // padded LDS row stride (shorts)
__global__ __launch_bounds__(256) void attn(
    const short* __restrict__ Qg, const short* __restrict__ Kg,
    const short* __restrict__ Vg, short* __restrict__ Yo)
{
  __shared__ short Ks[64 * LDK];
  __shared__ short Vs[64 * LDK];

  const int tid = threadIdx.x;
  const int lane = tid & 63;
  const int w = tid >> 6;
  const int lq = lane >> 4, lm = lane & 15;
  const int bh = blockIdx.y;
  const int b = bh >> 4, h = bh & 15;
  const size_t base = (size_t)bh * T_ * HS_;
  const short* __restrict__ Kb = Kg + base;
  const short* __restrict__ Vb = Vg + base;
  const float sf = 0.125f * 1.44269504089f;  // 1/sqrt(HS) * log2(e)

  // staging map: thread handles rows sr and sr+32, 16B chunk sc
  const int sr = tid >> 3;
  const int sc = (tid & 7) * 8;

#pragma unroll 1
  for (int half = 0; half < 2; ++half) {
    const int qt = half ? (int)blockIdx.x : 31 - (int)blockIdx.x;
    const int q0 = qt * 64;
    const int q = q0 + w * 16 + lm;          // this lane's q-row

    // Q fragment (B-layout): lane holds Q[q][lq*8+j (+32)]
    const short8 qf0 = *(const short8*)&Qg[base + (size_t)q * HS_ + lq * 8];
    const short8 qf1 = *(const short8*)&Qg[base + (size_t)q * HS_ + 32 + lq * 8];

    float m_run = -3.0e38f, l_run = 0.0f;    // per-lane (per q-row) state
    f32x4 o_acc[4] = {};                     // O^T: d = di*16+lq*4+i, col q

    // prefetch tile kt=0
    short8 pk0 = *(const short8*)&Kb[(size_t)sr * HS_ + sc];
    short8 pk1 = *(const short8*)&Kb[(size_t)(32 + sr) * HS_ + sc];
    short8 pv0 = *(const short8*)&Vb[(size_t)sr * T_ + sc];
    short8 pv1 = *(const short8*)&Vb[(size_t)(32 + sr) * T_ + sc];

#pragma unroll 1
    for (int kt = 0; kt <= qt; ++kt) {
      const int kv0 = kt * 64;

      __syncthreads();   // prior iteration's LDS reads complete
      *(short8*)&Ks[sr * LDK + sc] = pk0;
      *(short8*)&Ks[(32 + sr) * LDK + sc] = pk1;
      *(short8*)&Vs[sr * LDK + sc] = pv0;
      *(short8*)&Vs[(32 + sr) * LDK + sc] = pv1;
      __syncthreads();   // staging visible

      if (kt < qt) {     // prefetch next tile (latency hidden by compute)
        const int nk = kv0 + 64;
        pk0 = *(const short8*)&Kb[(size_t)(nk + sr) * HS_ + sc];
        pk1 = *(const short8*)&Kb[(size_t)(nk + 32 + sr) * HS_ + sc];
        pv0 = *(const short8*)&Vb[(size_t)sr * T_ + nk + sc];
        pv1 = *(const short8*)&Vb[(size_t)(32 + sr) * T_ + nk + sc];
      }

      // ---- S^T = K Q^T: sv[ni][i] = S[q][kv0 + ni*16 + lq*4 + i] ----
      f32x4 sv[4];
#pragma unroll
      for (int ni = 0; ni < 4; ++ni) {
        const short8 kf0 = *(const short8*)&Ks[(ni * 16 + lm) * LDK + lq * 8];
        const short8 kf1 = *(const short8*)&Ks[(ni * 16 + lm) * LDK + 32 + lq * 8];
        f32x4 s = {};
        s = __builtin_amdgcn_mfma_f32_16x16x32_bf16(kf0, qf0, s, 0, 0, 0);
        sv[ni] = __builtin_amdgcn_mfma_f32_16x16x32_bf16(kf1, qf1, s, 0, 0, 0);
      }

      if (kt == qt) {   // causal mask on diagonal tile (raw scores)
#pragma unroll
        for (int ni = 0; ni < 4; ++ni) {
          const int kvb = kv0 + ni * 16 + lq * 4;
#pragma unroll
          for (int i = 0; i < 4; ++i)
            if (kvb + i > q) sv[ni][i] = -3.0e38f;
        }
      }

      // ---- online softmax: in-register reduce + 2 cross-quad shuffles ----
      float v = fmaxf(fmaxf(fmaxf(sv[0][0], sv[0][1]), fmaxf(sv[0][2], sv[0][3])),
                      fmaxf(fmaxf(sv[1][0], sv[1][1]), fmaxf(sv[1][2], sv[1][3])));
      v = fmaxf(v, fmaxf(fmaxf(fmaxf(sv[2][0], sv[2][1]), fmaxf(sv[2][2], sv[2][3])),
                         fmaxf(fmaxf(sv[3][0], sv[3][1]), fmaxf(sv[3][2], sv[3][3]))));
      v = fmaxf(v, __shfl_xor(v, 16));
      v = fmaxf(v, __shfl_xor(v, 32));
      const float mnew = fmaxf(m_run, v);
      const float alpha = __builtin_amdgcn_exp2f((m_run - mnew) * sf);
      const float nb = -mnew * sf;
      m_run = mnew;

      // P = exp2(sf*s - sf*mnew)  (scale folded into exp2 arg)
#pragma unroll
      for (int ni = 0; ni < 4; ++ni)
#pragma unroll
        for (int i = 0; i < 4; ++i)
          sv[ni][i] = __builtin_amdgcn_exp2f(__builtin_fmaf(sv[ni][i], sf, nb));

      float s = ((sv[0][0] + sv[0][1]) + (sv[0][2] + sv[0][3]))
              + ((sv[1][0] + sv[1][1]) + (sv[1][2] + sv[1][3]))
              + ((sv[2][0] + sv[2][1]) + (sv[2][2] + sv[2][3]))
              + ((sv[3][0] + sv[3][1]) + (sv[3][2] + sv[3][3]));
      s += __shfl_xor(s, 16);
      s += __shfl_xor(s, 32);
      l_run = l_run * alpha + s;

#pragma unroll
      for (int di = 0; di < 4; ++di)
#pragma unroll
        for (int i = 0; i < 4; ++i)
          o_acc[di][i] *= alpha;

      // ---- pack P to bf16 (packed cvt), already in B-layout ----
      short4v p4[4];
#pragma unroll
      for (int ni = 0; ni < 4; ++ni) {
        union { short4v s4; unsigned u[2]; } pk;
        pk.u[0] = pk_bf16(sv[ni][0], sv[ni][1]);
        pk.u[1] = pk_bf16(sv[ni][2], sv[ni][3]);
        p4[ni] = pk.s4;
      }

      // ---- O^T += V^T P^T  (16x16x16 bf16 MFMA), V^T frags from LDS ----
#pragma unroll
      for (int di = 0; di < 4; ++di) {
#pragma unroll
        for (int ni = 0; ni < 4; ++ni) {
          const short4v vfr = *(const short4v*)&Vs[(di * 16 + lm) * LDK + ni * 16 + lq * 4];
          o_acc[di] = __builtin_amdgcn_mfma_f32_16x16x16bf16_1k(vfr, p4[ni], o_acc[di], 0, 0, 0);
        }
      }
    }

    // ---- epilogue: normalize, store Y bf16 [B,T,C], 4x b64 per lane ----
    const float rl = 1.0f / l_run;
    const size_t rowo = ((size_t)(b * T_ + q)) * C_ + h * HS_;
#pragma unroll
    for (int di = 0; di < 4; ++di) {
      union { short4v s4; unsigned u[2]; } pk;
      pk.u[0] = pk_bf16(o_acc[di][0] * rl, o_acc[di][1] * rl);
      pk.u[1] = pk_bf16(o_acc[di][2] * rl, o_acc[di][3] * rl);
      *(short4v*)&Yo[rowo + di * 16 + lq * 4] = pk.s4;
    }
  }
}

// ============================================================
extern "C" void kernel_launch(void* const* d_in, const int* in_sizes, int n_in,
                              void* d_out, int out_size, void* d_ws, size_t ws_size,
                              hipStream_t stream) {
  (void)in_sizes; (void)n_in; (void)out_size;
  const float* x     = (const float*)d_in[0];
  const float* Wqkv  = (const float*)d_in[1];
  const float* bqkv  = (const float*)d_in[2];
  const float* Wproj = (const float*)d_in[3];
  const float* bproj = (const float*)d_in[4];
  float* out = (float*)d_out;

  const size_t nWq = (size_t)N1_ * C_;        // 3,145,728
  const size_t nWp = (size_t)C_ * C_;         // 1,048,576
  const size_t nFull = (size_t)M_ * C_;       // 8,388,608
  const size_t nB = (size_t)T_ * C_;          // 2,097,152 per batch

  dim3 blk(256);
  const size_t need_batched = (nWq + nWp + 4 * nFull) * sizeof(short); // 75.6 MB

  if (ws_size >= need_batched) {
    // -------- fully batched pipeline --------
    short* Wq_bf = (short*)d_ws;
    short* Wp_bf = Wq_bf + nWq;
    short* S0    = Wp_bf + nWp;      // x_bf, later Y
    short* Qw    = S0 + nFull;
    short* Kw    = Qw + nFull;
    short* Vw    = Kw + nFull;       // transposed [BH][HS][T]

    conv_bf16<<<dim3((int)(nWq / 2048)), blk, 0, stream>>>(Wqkv, Wq_bf);
    conv_bf16<<<dim3((int)(nWp / 2048)), blk, 0, stream>>>(Wproj, Wp_bf);
    conv_bf16<<<dim3((int)(nFull / 2048)), blk, 0, stream>>>(x, S0);
    qkv_gemm<<<dim3(M_ / 128, N1_ / 128), blk, 0, stream>>>(S0, Wq_bf, bqkv, Qw, Kw, Vw);
    attn<<<dim3(16, BH_), blk, 0, stream>>>(Qw, Kw, Vw, S0);
    proj_gemm<<<dim3(M_ / 128, C_ / 128), blk, 0, stream>>>(S0, Wp_bf, bproj, out);
  } else {
    // -------- per-batch fallback (25.2 MB ws) --------
    short* Wq_bf = (short*)d_ws;
    short* Wp_bf = Wq_bf + nWq;
    short* S0    = Wp_bf + nWp;      // x_bf, later Y (per batch)
    short* Qw    = S0 + nB;
    short* Kw    = Qw + nB;
    short* Vw    = Kw + nB;

    conv_bf16<<<dim3((int)(nWq / 2048)), blk, 0, stream>>>(Wqkv, Wq_bf);
    conv_bf16<<<dim3((int)(nWp / 2048)), blk, 0, stream>>>(Wproj, Wp_bf);
    for (int b = 0; b < B_; ++b) {
      const float* xb = x   + (size_t)b * nB;
      float*       ob = out + (size_t)b * nB;
      conv_bf16<<<dim3((int)(nB / 2048)), blk, 0, stream>>>(xb, S0);
      qkv_gemm<<<dim3(T_ / 128, N1_ / 128), blk, 0, stream>>>(S0, Wq_bf, bqkv, Qw, Kw, Vw);
      attn<<<dim3(16, NH_), blk, 0, stream>>>(Qw, Kw, Vw, S0);
      proj_gemm<<<dim3(T_ / 128, C_ / 128), blk, 0, stream>>>(S0, Wp_bf, bproj, ob);
    }
  }
}